// Round 7
// baseline (1333.028 us; speedup 1.0000x reference)
//
#include <hip/hip_runtime.h>

#define NN 100000
#define NE 1600000
#define NG 128
#define DIM 128
#define OUTD 64
#define NL 4
#define SCAN_B 1024
#define NB ((NN + SCAN_B - 1) / SCAN_B)   // 98 scan blocks
#define NSL 8                              // XCD slices for scatter
#define SLN 12500                          // nodes per slice
#define SL_CH 4096                         // edges per scatter chunk
#define PGCOPY (5 * NG * DIM)              // one PG copy (per-XCD); 8 copies

typedef __attribute__((ext_vector_type(8))) short bf16x8;
typedef __attribute__((ext_vector_type(4))) float floatx4;

__device__ __forceinline__ float bf_lo(unsigned u) {
    union { unsigned u; float f; } c; c.u = u << 16; return c.f;
}
__device__ __forceinline__ float bf_hi(unsigned u) {
    union { unsigned u; float f; } c; c.u = u & 0xffff0000u; return c.f;
}
__device__ __forceinline__ unsigned f2bf(float x) {   // RNE
    union { float f; unsigned u; } c; c.f = x;
    return (c.u + 0x7fffu + ((c.u >> 16) & 1u)) >> 16;
}
__device__ __forceinline__ float bfs2f(short s) {
    union { unsigned u; float f; } c; c.u = ((unsigned)(unsigned short)s) << 16; return c.f;
}

// BN(train) fold: from stat = [sum(128) | sumsq(128)] derive a,c: bn(x)=a*x+c
__device__ __forceinline__ void bn_coef(const float* __restrict__ stat,
                                        const float* __restrict__ gamma,
                                        const float* __restrict__ beta,
                                        int f, float& a, float& c) {
    float mu = stat[f] * (1.0f / NN);
    float var = fmaf(-mu, mu, stat[DIM + f] * (1.0f / NN));
    a = gamma[f] * rsqrtf(var + 1e-5f);
    c = fmaf(-mu, a, beta[f]);
}

// ---------------------------------------------------------------------------
// CSR build, node-granular cursors (100K counters -> no atomic hot-spot)
__global__ void hist(const int* __restrict__ edst, int* __restrict__ deg) {
    int e = blockIdx.x * 256 + threadIdx.x;
    if (e < NE) atomicAdd(&deg[edst[e]], 1);
}

__global__ void scan_local(const int* __restrict__ deg, int* __restrict__ loc,
                           int* __restrict__ bsums) {
    __shared__ int s[256];
    int base = blockIdx.x * SCAN_B + threadIdx.x * 4;
    int d0 = 0, d1 = 0, d2 = 0, d3 = 0;
    if (base + 0 < NN) d0 = deg[base + 0];
    if (base + 1 < NN) d1 = deg[base + 1];
    if (base + 2 < NN) d2 = deg[base + 2];
    if (base + 3 < NN) d3 = deg[base + 3];
    int t4 = d0 + d1 + d2 + d3;
    s[threadIdx.x] = t4;
    __syncthreads();
    for (int off = 1; off < 256; off <<= 1) {
        int v = (threadIdx.x >= off) ? s[threadIdx.x - off] : 0;
        __syncthreads();
        s[threadIdx.x] += v;
        __syncthreads();
    }
    int excl = s[threadIdx.x] - t4;
    if (base + 0 < NN) loc[base + 0] = excl;
    if (base + 1 < NN) loc[base + 1] = excl + d0;
    if (base + 2 < NN) loc[base + 2] = excl + d0 + d1;
    if (base + 3 < NN) loc[base + 3] = excl + d0 + d1 + d2;
    if (threadIdx.x == 255) bsums[blockIdx.x] = s[255];
}

__global__ void scan_sums(int* __restrict__ bsums) {
    __shared__ int s[128];
    int v = (threadIdx.x < NB) ? bsums[threadIdx.x] : 0;
    s[threadIdx.x] = v;
    __syncthreads();
    for (int off = 1; off < 128; off <<= 1) {
        int u = (threadIdx.x >= off) ? s[threadIdx.x - off] : 0;
        __syncthreads();
        s[threadIdx.x] += u;
        __syncthreads();
    }
    if (threadIdx.x < NB) bsums[threadIdx.x] = s[threadIdx.x] - v;  // exclusive
}

__global__ void scan_add(const int* __restrict__ loc, const int* __restrict__ bsums,
                         int* __restrict__ offs, int* __restrict__ cur) {
    int i = blockIdx.x * 256 + threadIdx.x;
    if (i < NN) {
        int o = loc[i] + bsums[i >> 10];
        offs[i] = o;
        cur[i] = o;
    }
}

// XCD-sliced scatter: slice s (blockIdx.x) only handles dst in its 12500-node
// range; its ~800KB perm window stays one-XCD L2-resident until lines fill.
__global__ void scatter_sliced(const int* __restrict__ esrc, const int* __restrict__ edst,
                               int* __restrict__ cur, int* __restrict__ perm) {
    const unsigned lo = blockIdx.x * SLN, hi = lo + SLN;
    int base = blockIdx.y * SL_CH;
    int end = base + SL_CH; if (end > NE) end = NE;
    for (int e = base + threadIdx.x; e < end; e += 256) {
        unsigned d = (unsigned)edst[e];
        if (d >= lo && d < hi) {
            int pos = atomicAdd(&cur[d], 1);
            perm[pos] = esrc[e];
        }
    }
}

// ---------------------------------------------------------------------------
// fp32 -> bf16 convert (x once per call)
__global__ void to_bf16(const float* __restrict__ x, unsigned* __restrict__ xb) {
    size_t i = ((size_t)blockIdx.x * 256 + threadIdx.x) * 4;
    float4 v = *(const float4*)(x + i);
    uint2 o;
    o.x = f2bf(v.x) | (f2bf(v.y) << 16);
    o.y = f2bf(v.z) | (f2bf(v.w) << 16);
    *(uint2*)(xb + i / 2) = o;
}

// Build Wt[mat][n][k] bf16 from 8 fp32 weight matrices (once per call).
__global__ void build_wt(const float* __restrict__ W1, const float* __restrict__ W2,
                         unsigned short* __restrict__ Wt) {
    int b = blockIdx.x;              // 0..7: layer = b>>1, which = b&1
    const float* W = ((b & 1) ? W2 : W1) + (size_t)(b >> 1) * DIM * DIM;
    unsigned short* O = Wt + (size_t)b * DIM * DIM;
    int i = blockIdx.y * 2048 + threadIdx.x;
    for (int j = 0; j < 8; ++j, i += 256) {
        int k = i >> 7, n = i & 127;
        O[n * DIM + k] = (unsigned short)f2bf(W[i]);
    }
}

// ---------------------------------------------------------------------------
// Fused pull-aggregation + per-graph pooling.
// Wave = 1 node (64 lanes). Half-wave (32 lanes) covers a full 256B row via
// uint2; the two halves process different edges (2 edges per gather instr).
// Pool: T(h[node]) block-reduced in LDS, flushed to the per-XCD PG copy.
template<int TR>
__global__ __launch_bounds__(256)
void csr_agg_pool(const unsigned* __restrict__ hq, const int* __restrict__ offs,
                  const int* __restrict__ perm, const float* __restrict__ eps, int l,
                  const float* __restrict__ stat, const float* __restrict__ gamma,
                  const float* __restrict__ beta, const int* __restrict__ gid,
                  float* __restrict__ pg, unsigned* __restrict__ outq) {
    __shared__ float pool_s[4][DIM];
    __shared__ int gids[4];
    const int w = threadIdx.x >> 6;               // wave = node slot (NN%4==0)
    const int node = blockIdx.x * 4 + w;
    const int lane = threadIdx.x & 63;
    const int half = lane >> 5, sl = lane & 31;
    const int start = offs[node];
    const int end = (node == NN - 1) ? NE : offs[node + 1];
    const int f = sl * 4;

    float A0 = 0.f, C0 = 0.f, A1 = 0.f, C1 = 0.f;
    float A2 = 0.f, C2 = 0.f, A3 = 0.f, C3 = 0.f;
    if (TR) {
        bn_coef(stat, gamma, beta, f + 0, A0, C0);
        bn_coef(stat, gamma, beta, f + 1, A1, C1);
        bn_coef(stat, gamma, beta, f + 2, A2, C2);
        bn_coef(stat, gamma, beta, f + 3, A3, C3);
    }

    // self term + pool contribution
    uint2 sv = *(const uint2*)(hq + (size_t)node * 64 + sl * 2);
    float t0 = bf_lo(sv.x), t1 = bf_hi(sv.x), t2 = bf_lo(sv.y), t3 = bf_hi(sv.y);
    if (TR) {
        t0 = fmaxf(fmaf(t0, A0, C0), 0.f); t1 = fmaxf(fmaf(t1, A1, C1), 0.f);
        t2 = fmaxf(fmaf(t2, A2, C2), 0.f); t3 = fmaxf(fmaf(t3, A3, C3), 0.f);
    }
    if (half == 0) *(float4*)&pool_s[w][f] = make_float4(t0, t1, t2, t3);
    if (lane == 0) gids[w] = gid[node];

    const float e1 = 1.0f + eps[l];
    float acc0 = half ? 0.f : e1 * t0, acc1 = half ? 0.f : e1 * t1;
    float acc2 = half ? 0.f : e1 * t2, acc3 = half ? 0.f : e1 * t3;

    int j = start;
    for (; j + 15 < end; j += 16) {               // half h takes [j+8h, j+8h+8)
        const int* pp = perm + j + half * 8;
        int idx[8];
#pragma unroll
        for (int q = 0; q < 8; ++q) idx[q] = pp[q];
        uint2 u[8];
#pragma unroll
        for (int q = 0; q < 8; ++q)
            u[q] = *(const uint2*)(hq + (size_t)idx[q] * 64 + sl * 2);
#pragma unroll
        for (int q = 0; q < 8; ++q) {
            float p0 = bf_lo(u[q].x), p1 = bf_hi(u[q].x);
            float p2 = bf_lo(u[q].y), p3 = bf_hi(u[q].y);
            if (TR) {
                p0 = fmaxf(fmaf(p0, A0, C0), 0.f); p1 = fmaxf(fmaf(p1, A1, C1), 0.f);
                p2 = fmaxf(fmaf(p2, A2, C2), 0.f); p3 = fmaxf(fmaf(p3, A3, C3), 0.f);
            }
            acc0 += p0; acc1 += p1; acc2 += p2; acc3 += p3;
        }
    }
    for (; j < end; j += 2) {                     // tail: half h takes j+h
        int jq = j + half;
        if (jq < end) {
            uint2 u = *(const uint2*)(hq + (size_t)perm[jq] * 64 + sl * 2);
            float p0 = bf_lo(u.x), p1 = bf_hi(u.x);
            float p2 = bf_lo(u.y), p3 = bf_hi(u.y);
            if (TR) {
                p0 = fmaxf(fmaf(p0, A0, C0), 0.f); p1 = fmaxf(fmaf(p1, A1, C1), 0.f);
                p2 = fmaxf(fmaf(p2, A2, C2), 0.f); p3 = fmaxf(fmaf(p3, A3, C3), 0.f);
            }
            acc0 += p0; acc1 += p1; acc2 += p2; acc3 += p3;
        }
    }

    // combine halves, write aggregated row
    acc0 += __shfl_xor(acc0, 32); acc1 += __shfl_xor(acc1, 32);
    acc2 += __shfl_xor(acc2, 32); acc3 += __shfl_xor(acc3, 32);
    if (half == 0) {
        uint2 o;
        o.x = f2bf(acc0) | (f2bf(acc1) << 16);
        o.y = f2bf(acc2) | (f2bf(acc3) << 16);
        *(uint2*)(outq + (size_t)node * 64 + sl * 2) = o;
    }

    // pool flush (gid sorted => block usually single-graph)
    __syncthreads();
    if (gids[0] == gids[3]) {
        if (w == 0) {
            int g = gids[0];
            for (int ff = lane; ff < DIM; ff += 64) {
                float s = pool_s[0][ff] + pool_s[1][ff] + pool_s[2][ff] + pool_s[3][ff];
                unsafeAtomicAdd(&pg[g * DIM + ff], s);
            }
        }
    } else {
        int g = gids[w];
        for (int ff = lane; ff < DIM; ff += 64)
            unsafeAtomicAdd(&pg[g * DIM + ff], pool_s[w][ff]);
    }
}

// ---------------------------------------------------------------------------
// Y[NN x 128] = T(X) @ W + bias via mfma_f32_16x16x32_bf16, no LDS staging.
// Fused epilogue: bf16 store + per-column sum/sumsq -> ostat[0:128]/[128:256].
template<int TR>
__global__ __launch_bounds__(256, 2)
void gemm_mfma(const unsigned short* __restrict__ X, const unsigned short* __restrict__ Wt,
               const float* __restrict__ bias,
               const float* __restrict__ stat, const float* __restrict__ gamma,
               const float* __restrict__ beta,
               unsigned short* __restrict__ Y, float* __restrict__ ostat) {
    __shared__ float red[4 * 256];
    __shared__ float tatc[2 * DIM];
    const int t = threadIdx.x;
    const int w = t >> 6, lane = t & 63;
    const int quad = lane >> 4, m = lane & 15;
    const int rowbase = blockIdx.x * 128 + w * 32;

    if (TR) {
        if (t < DIM) {
            float a, c;
            bn_coef(stat, gamma, beta, t, a, c);
            tatc[t] = a; tatc[DIM + t] = c;
        }
        __syncthreads();
    }

    bf16x8 a[2][4];
#pragma unroll
    for (int rt = 0; rt < 2; ++rt) {
        int row = rowbase + rt * 16 + m;
        if (row > NN - 1) row = NN - 1;
        const unsigned short* xr = X + (size_t)row * DIM + quad * 8;
#pragma unroll
        for (int ks = 0; ks < 4; ++ks) {
            bf16x8 v = *(const bf16x8*)(xr + ks * 32);
            if (TR) {
                int kk = ks * 32 + quad * 8;
#pragma unroll
                for (int j = 0; j < 8; ++j) {
                    float fv = bfs2f(v[j]);
                    fv = fmaxf(fmaf(fv, tatc[kk + j], tatc[DIM + kk + j]), 0.f);
                    v[j] = (short)f2bf(fv);
                }
            }
            a[rt][ks] = v;
        }
    }

    floatx4 acc[2][8];
#pragma unroll
    for (int rt = 0; rt < 2; ++rt)
#pragma unroll
        for (int ct = 0; ct < 8; ++ct) acc[rt][ct] = (floatx4)0.f;

#pragma unroll
    for (int ct = 0; ct < 8; ++ct) {
        const unsigned short* wr = Wt + (size_t)(ct * 16 + m) * DIM + quad * 8;
#pragma unroll
        for (int ks = 0; ks < 4; ++ks) {
            bf16x8 b = *(const bf16x8*)(wr + ks * 32);
            acc[0][ct] = __builtin_amdgcn_mfma_f32_16x16x32_bf16(a[0][ks], b, acc[0][ct], 0, 0, 0);
            acc[1][ct] = __builtin_amdgcn_mfma_f32_16x16x32_bf16(a[1][ks], b, acc[1][ct], 0, 0, 0);
        }
    }

    // epilogue: bias + bf16 store + masked column stats
#pragma unroll
    for (int ct = 0; ct < 8; ++ct) {
        int col = ct * 16 + m;
        float bv = bias[col];
        float s = 0.f, q = 0.f;
#pragma unroll
        for (int rt = 0; rt < 2; ++rt) {
#pragma unroll
            for (int r = 0; r < 4; ++r) {
                int row = rowbase + rt * 16 + quad * 4 + r;
                float val = acc[rt][ct][r] + bv;
                if (row < NN) {
                    Y[(size_t)row * DIM + col] = (unsigned short)f2bf(val);
                    s += val;
                    q = fmaf(val, val, q);
                }
            }
        }
        s += __shfl_xor(s, 16); s += __shfl_xor(s, 32);
        q += __shfl_xor(q, 16); q += __shfl_xor(q, 32);
        if (quad == 0) { red[w * 256 + col] = s; red[w * 256 + 128 + col] = q; }
    }
    __syncthreads();
    if (t < 256) {
        float tot = red[t] + red[256 + t] + red[512 + t] + red[768 + t];
        unsafeAtomicAdd(&ostat[t], tot);
    }
}

// Standalone pool for the final hidden layer (writes PG copy 0).
template<int TR>
__global__ void pool_nodes(const unsigned* __restrict__ hq, const int* __restrict__ gid,
                           const float* __restrict__ stat, const float* __restrict__ gamma,
                           const float* __restrict__ beta, float* __restrict__ pg) {
    const int lane = threadIdx.x;            // 64 threads, feature pair per lane
    int start = blockIdx.x * 32;
    int end = start + 32;
    if (end > NN) end = NN;
    int f = lane * 2;
    float a0 = 0.f, c0 = 0.f, a1 = 0.f, c1 = 0.f;
    if (TR) {
        bn_coef(stat, gamma, beta, f, a0, c0);
        bn_coef(stat, gamma, beta, f + 1, a1, c1);
    }
    int cur = gid[start];
    float acc0 = 0.f, acc1 = 0.f;
    for (int i = start; i < end; ++i) {
        int g = gid[i];
        if (g != cur) {
            unsafeAtomicAdd(&pg[cur * DIM + f], acc0);
            unsafeAtomicAdd(&pg[cur * DIM + f + 1], acc1);
            acc0 = 0.f; acc1 = 0.f;
            cur = g;
        }
        unsigned u = hq[(size_t)i * 64 + lane];
        float x0 = bf_lo(u), x1 = bf_hi(u);
        if (TR) {
            x0 = fmaxf(fmaf(x0, a0, c0), 0.f);
            x1 = fmaxf(fmaf(x1, a1, c1), 0.f);
        }
        acc0 += x0; acc1 += x1;
    }
    unsafeAtomicAdd(&pg[cur * DIM + f], acc0);
    unsafeAtomicAdd(&pg[cur * DIM + f + 1], acc1);
}

// score over 8 per-XCD PG copies
__global__ void final_score(const float* __restrict__ pg, const float* __restrict__ predW,
                            const float* __restrict__ predb, float* __restrict__ out) {
    int g = blockIdx.x;
    int o = threadIdx.x;
    float acc = 0.f;
    for (int l = 0; l <= NL; ++l) {
        acc += predb[l * OUTD + o];
        const float* w = predW + (size_t)l * DIM * OUTD;
        for (int cp = 0; cp < 8; ++cp) {
            const float* pgr = pg + cp * PGCOPY + ((size_t)l * NG + g) * DIM;
#pragma unroll 8
            for (int k = 0; k < DIM; ++k)
                acc = fmaf(pgr[k], w[k * OUTD + o], acc);
        }
    }
    out[g * OUTD + o] = acc;
}

extern "C" void kernel_launch(void* const* d_in, const int* in_sizes, int n_in,
                              void* d_out, int out_size, void* d_ws, size_t ws_size,
                              hipStream_t stream) {
    const float* x     = (const float*)d_in[0];
    const int*   esrc  = (const int*)d_in[1];
    const int*   edst  = (const int*)d_in[2];
    const int*   gid   = (const int*)d_in[3];
    const float* eps   = (const float*)d_in[4];
    const float* W1    = (const float*)d_in[5];
    const float* b1    = (const float*)d_in[6];
    const float* g1    = (const float*)d_in[7];
    const float* be1   = (const float*)d_in[8];
    const float* W2    = (const float*)d_in[9];
    const float* b2    = (const float*)d_in[10];
    const float* g2    = (const float*)d_in[11];
    const float* be2   = (const float*)d_in[12];
    const float* predW = (const float*)d_in[13];
    const float* predb = (const float*)d_in[14];
    float* out = (float*)d_out;

    // ws layout (~88 MB): 3 bf16 node buffers + Wt + [PGx8|STATS|DEG one-memset
    // region] + CSR arrays
    unsigned short* XB = (unsigned short*)d_ws;
    unsigned short* A  = XB + (size_t)NN * DIM;
    unsigned short* B  = A + (size_t)NN * DIM;
    unsigned short* WT = B + (size_t)NN * DIM;
    float* PG    = (float*)(WT + 8 * DIM * DIM);   // 8 per-XCD copies
    float* STATS = PG + 8 * PGCOPY;                // 4 layers x 512: [S1|SQ1|S2|SQ2]
    int* DEG  = (int*)(STATS + NL * 512);
    int* LOC  = DEG + NN;
    int* OFFS = LOC + NN;
    int* CUR  = OFFS + NN;
    int* BS   = CUR + NN;
    int* PERM = BS + 128;

    // one memset covers PG copies + all per-layer stats + DEG (contiguous)
    hipMemsetAsync(PG, 0, (8 * PGCOPY + NL * 512) * sizeof(float) + NN * sizeof(int),
                   stream);

    // ---- one-time per call: CSR build, x->bf16, transposed bf16 weights
    const int eBlocks = (NE + 255) / 256;
    hist<<<eBlocks, 256, 0, stream>>>(edst, DEG);
    scan_local<<<NB, 256, 0, stream>>>(DEG, LOC, BS);
    scan_sums<<<1, 128, 0, stream>>>(BS);
    scan_add<<<(NN + 255) / 256, 256, 0, stream>>>(LOC, BS, OFFS, CUR);
    scatter_sliced<<<dim3(NSL, (NE + SL_CH - 1) / SL_CH), 256, 0, stream>>>(esrc, edst,
                                                                            CUR, PERM);
    to_bf16<<<(NN * DIM) / 1024, 256, 0, stream>>>(x, (unsigned*)XB);
    build_wt<<<dim3(8, 8), 256, 0, stream>>>(W1, W2, WT);

    const int aggBlocks  = NN / 4;       // NN % 4 == 0
    const int gemmBlocks = (NN + 127) / 128;

    const unsigned* h = (const unsigned*)XB;
    for (int l = 0; l < NL; ++l) {
        float* STATL = STATS + l * 512;
        if (l == 0) {
            csr_agg_pool<0><<<aggBlocks, 256, 0, stream>>>(h, OFFS, PERM, eps, l,
                                                           nullptr, nullptr, nullptr,
                                                           gid, PG, (unsigned*)B);
        } else {
            const float* prevS = STATS + (l - 1) * 512 + 256;
            csr_agg_pool<1><<<aggBlocks, 256, 0, stream>>>(h, OFFS, PERM, eps, l,
                                                           prevS, g2 + (l - 1) * DIM,
                                                           be2 + (l - 1) * DIM,
                                                           gid, PG + l * NG * DIM,
                                                           (unsigned*)B);
        }
        gemm_mfma<0><<<gemmBlocks, 256, 0, stream>>>(B, WT + (size_t)(2 * l) * DIM * DIM,
                                                     b1 + l * DIM, nullptr, nullptr, nullptr,
                                                     B, STATL);
        gemm_mfma<1><<<gemmBlocks, 256, 0, stream>>>(B, WT + (size_t)(2 * l + 1) * DIM * DIM,
                                                     b2 + l * DIM, STATL, g1 + l * DIM,
                                                     be1 + l * DIM, A, STATL + 256);
        h = (const unsigned*)A;
    }
    pool_nodes<1><<<(NN + 31) / 32, 64, 0, stream>>>(h, gid, STATS + (NL - 1) * 512 + 256,
                                                     g2 + (NL - 1) * DIM, be2 + (NL - 1) * DIM,
                                                     PG + NL * NG * DIM);
    final_score<<<NG, OUTD, 0, stream>>>(PG, predW, predb, out);
}

// Round 8
// 1198.712 us; speedup vs baseline: 1.1121x; 1.1121x over previous
//
#include <hip/hip_runtime.h>

#define NN 100000
#define NE 1600000
#define NG 128
#define DIM 128
#define OUTD 64
#define NL 4
#define SCAN_B 1024
#define NB ((NN + SCAN_B - 1) / SCAN_B)   // 98 scan blocks
#define NSL 8                              // XCD slices for scatter
#define SLN 12500                          // nodes per slice
#define SL_CH 4096                         // edges per scatter chunk

typedef __attribute__((ext_vector_type(8))) short bf16x8;
typedef __attribute__((ext_vector_type(4))) float floatx4;

__device__ __forceinline__ float bf_lo(unsigned u) {
    union { unsigned u; float f; } c; c.u = u << 16; return c.f;
}
__device__ __forceinline__ float bf_hi(unsigned u) {
    union { unsigned u; float f; } c; c.u = u & 0xffff0000u; return c.f;
}
__device__ __forceinline__ unsigned f2bf(float x) {   // RNE
    union { float f; unsigned u; } c; c.f = x;
    return (c.u + 0x7fffu + ((c.u >> 16) & 1u)) >> 16;
}
__device__ __forceinline__ float bfs2f(short s) {
    union { unsigned u; float f; } c; c.u = ((unsigned)(unsigned short)s) << 16; return c.f;
}

// BN(train) fold: from stat = [sum(128) | sumsq(128)] derive a,c: bn(x)=a*x+c
__device__ __forceinline__ void bn_coef(const float* __restrict__ stat,
                                        const float* __restrict__ gamma,
                                        const float* __restrict__ beta,
                                        int f, float& a, float& c) {
    float mu = stat[f] * (1.0f / NN);
    float var = fmaf(-mu, mu, stat[DIM + f] * (1.0f / NN));
    a = gamma[f] * rsqrtf(var + 1e-5f);
    c = fmaf(-mu, a, beta[f]);
}

// ---------------------------------------------------------------------------
// CSR build, node-granular cursors (100K counters -> no atomic hot-spot)
__global__ void hist(const int* __restrict__ edst, int* __restrict__ deg) {
    int e = blockIdx.x * 256 + threadIdx.x;
    if (e < NE) atomicAdd(&deg[edst[e]], 1);
}

__global__ void scan_local(const int* __restrict__ deg, int* __restrict__ loc,
                           int* __restrict__ bsums) {
    __shared__ int s[256];
    int base = blockIdx.x * SCAN_B + threadIdx.x * 4;
    int d0 = 0, d1 = 0, d2 = 0, d3 = 0;
    if (base + 0 < NN) d0 = deg[base + 0];
    if (base + 1 < NN) d1 = deg[base + 1];
    if (base + 2 < NN) d2 = deg[base + 2];
    if (base + 3 < NN) d3 = deg[base + 3];
    int t4 = d0 + d1 + d2 + d3;
    s[threadIdx.x] = t4;
    __syncthreads();
    for (int off = 1; off < 256; off <<= 1) {
        int v = (threadIdx.x >= off) ? s[threadIdx.x - off] : 0;
        __syncthreads();
        s[threadIdx.x] += v;
        __syncthreads();
    }
    int excl = s[threadIdx.x] - t4;
    if (base + 0 < NN) loc[base + 0] = excl;
    if (base + 1 < NN) loc[base + 1] = excl + d0;
    if (base + 2 < NN) loc[base + 2] = excl + d0 + d1;
    if (base + 3 < NN) loc[base + 3] = excl + d0 + d1 + d2;
    if (threadIdx.x == 255) bsums[blockIdx.x] = s[255];
}

__global__ void scan_sums(int* __restrict__ bsums) {
    __shared__ int s[128];
    int v = (threadIdx.x < NB) ? bsums[threadIdx.x] : 0;
    s[threadIdx.x] = v;
    __syncthreads();
    for (int off = 1; off < 128; off <<= 1) {
        int u = (threadIdx.x >= off) ? s[threadIdx.x - off] : 0;
        __syncthreads();
        s[threadIdx.x] += u;
        __syncthreads();
    }
    if (threadIdx.x < NB) bsums[threadIdx.x] = s[threadIdx.x] - v;  // exclusive
}

__global__ void scan_add(const int* __restrict__ loc, const int* __restrict__ bsums,
                         int* __restrict__ offs, int* __restrict__ cur) {
    int i = blockIdx.x * 256 + threadIdx.x;
    if (i < NN) {
        int o = loc[i] + bsums[i >> 10];
        offs[i] = o;
        cur[i] = o;
    }
}

// XCD-sliced scatter: slice s (blockIdx.x) only handles dst in its 12500-node
// range; its ~800KB perm window stays one-XCD L2-resident until lines fill.
__global__ void scatter_sliced(const int* __restrict__ esrc, const int* __restrict__ edst,
                               int* __restrict__ cur, int* __restrict__ perm) {
    const unsigned lo = blockIdx.x * SLN, hi = lo + SLN;
    int base = blockIdx.y * SL_CH;
    int end = base + SL_CH; if (end > NE) end = NE;
    for (int e = base + threadIdx.x; e < end; e += 256) {
        unsigned d = (unsigned)edst[e];
        if (d >= lo && d < hi) {
            int pos = atomicAdd(&cur[d], 1);
            perm[pos] = esrc[e];
        }
    }
}

// ---------------------------------------------------------------------------
// fp32 -> bf16 convert (x once per call)
__global__ void to_bf16(const float* __restrict__ x, unsigned* __restrict__ xb) {
    size_t i = ((size_t)blockIdx.x * 256 + threadIdx.x) * 4;
    float4 v = *(const float4*)(x + i);
    uint2 o;
    o.x = f2bf(v.x) | (f2bf(v.y) << 16);
    o.y = f2bf(v.z) | (f2bf(v.w) << 16);
    *(uint2*)(xb + i / 2) = o;
}

// Build Wt[mat][n][k] bf16 from 8 fp32 weight matrices (once per call).
__global__ void build_wt(const float* __restrict__ W1, const float* __restrict__ W2,
                         unsigned short* __restrict__ Wt) {
    int b = blockIdx.x;              // 0..7: layer = b>>1, which = b&1
    const float* W = ((b & 1) ? W2 : W1) + (size_t)(b >> 1) * DIM * DIM;
    unsigned short* O = Wt + (size_t)b * DIM * DIM;
    int i = blockIdx.y * 2048 + threadIdx.x;
    for (int j = 0; j < 8; ++j, i += 256) {
        int k = i >> 7, n = i & 127;
        O[n * DIM + k] = (unsigned short)f2bf(W[i]);
    }
}

// ---------------------------------------------------------------------------
// Pull aggregation in bf16: out[n] = (1+eps)*T(h[n]) + sum_{src} T(h[src]).
// 256 threads = 4 waves; wave = 1 node; lane owns feature pair (dword).
// R6-proven thin-wave shape + one-iteration index prefetch: the next batch of
// 8 perm indices is loaded while the current 8 row-gathers are in flight.
template<int TR>
__global__ void csr_agg(const unsigned* __restrict__ hq, const int* __restrict__ offs,
                        const int* __restrict__ perm, const float* __restrict__ eps, int l,
                        const float* __restrict__ stat, const float* __restrict__ gamma,
                        const float* __restrict__ beta, unsigned* __restrict__ outq) {
    int node = blockIdx.x * 4 + (threadIdx.x >> 6);
    int lane = threadIdx.x & 63;
    if (node >= NN) return;
    int start = offs[node];
    int end = (node == NN - 1) ? NE : offs[node + 1];
    int f = lane * 2;
    float a0 = 0.f, c0 = 0.f, a1 = 0.f, c1 = 0.f;
    if (TR) {
        bn_coef(stat, gamma, beta, f, a0, c0);
        bn_coef(stat, gamma, beta, f + 1, a1, c1);
    }
    unsigned v = hq[(size_t)node * 64 + lane];
    float x0 = bf_lo(v), x1 = bf_hi(v);
    if (TR) {
        x0 = fmaxf(fmaf(x0, a0, c0), 0.f);
        x1 = fmaxf(fmaf(x1, a1, c1), 0.f);
    }
    float e1 = 1.0f + eps[l];
    float acc0 = e1 * x0, acc1 = e1 * x1;

    int j = start;
    int nidx[8];
    bool have = (j + 7 < end);
    if (have) {
#pragma unroll
        for (int q = 0; q < 8; ++q) nidx[q] = perm[j + q];
    }
    while (have) {
        unsigned u[8];
#pragma unroll
        for (int q = 0; q < 8; ++q)
            u[q] = hq[(size_t)nidx[q] * 64 + lane];
        j += 8;
        have = (j + 7 < end);
        if (have) {
#pragma unroll
            for (int q = 0; q < 8; ++q) nidx[q] = perm[j + q];   // overlaps gathers
        }
        float s0 = 0.f, s1 = 0.f;
#pragma unroll
        for (int q = 0; q < 8; ++q) {
            float p0 = bf_lo(u[q]), p1 = bf_hi(u[q]);
            if (TR) {
                p0 = fmaxf(fmaf(p0, a0, c0), 0.f);
                p1 = fmaxf(fmaf(p1, a1, c1), 0.f);
            }
            s0 += p0; s1 += p1;
        }
        acc0 += s0; acc1 += s1;
    }
    for (; j < end; ++j) {
        unsigned u0 = hq[(size_t)perm[j] * 64 + lane];
        float p0 = bf_lo(u0), p1 = bf_hi(u0);
        if (TR) {
            p0 = fmaxf(fmaf(p0, a0, c0), 0.f);
            p1 = fmaxf(fmaf(p1, a1, c1), 0.f);
        }
        acc0 += p0; acc1 += p1;
    }
    outq[(size_t)node * 64 + lane] = f2bf(acc0) | (f2bf(acc1) << 16);
}

// ---------------------------------------------------------------------------
// Y[NN x 128] = T(X) @ W + bias via mfma_f32_16x16x32_bf16, no LDS staging.
// 64 rows/block (1563 blocks, ~6 blocks/CU): wave = 16 rows x 128 cols,
// 32 MFMAs — half the per-wave serial chain of the previous 128-row tiling,
// twice the resident blocks for latency hiding.
// Fused epilogue: bf16 store + per-column sum/sumsq -> ostat[0:128]/[128:256].
template<int TR>
__global__ __launch_bounds__(256, 4)
void gemm_mfma(const unsigned short* __restrict__ X, const unsigned short* __restrict__ Wt,
               const float* __restrict__ bias,
               const float* __restrict__ stat, const float* __restrict__ gamma,
               const float* __restrict__ beta,
               unsigned short* __restrict__ Y, float* __restrict__ ostat) {
    __shared__ float red[4 * 256];
    __shared__ float tatc[2 * DIM];
    const int t = threadIdx.x;
    const int w = t >> 6, lane = t & 63;
    const int quad = lane >> 4, m = lane & 15;
    const int rowbase = blockIdx.x * 64 + w * 16;

    if (TR) {
        if (t < DIM) {
            float a, c;
            bn_coef(stat, gamma, beta, t, a, c);
            tatc[t] = a; tatc[DIM + t] = c;
        }
        __syncthreads();
    }

    bf16x8 a[4];
    {
        int row = rowbase + m;
        if (row > NN - 1) row = NN - 1;
        const unsigned short* xr = X + (size_t)row * DIM + quad * 8;
#pragma unroll
        for (int ks = 0; ks < 4; ++ks) {
            bf16x8 v = *(const bf16x8*)(xr + ks * 32);
            if (TR) {
                int kk = ks * 32 + quad * 8;
#pragma unroll
                for (int j = 0; j < 8; ++j) {
                    float fv = bfs2f(v[j]);
                    fv = fmaxf(fmaf(fv, tatc[kk + j], tatc[DIM + kk + j]), 0.f);
                    v[j] = (short)f2bf(fv);
                }
            }
            a[ks] = v;
        }
    }

    floatx4 acc[8];
#pragma unroll
    for (int ct = 0; ct < 8; ++ct) acc[ct] = (floatx4)0.f;

#pragma unroll
    for (int ct = 0; ct < 8; ++ct) {
        const unsigned short* wr = Wt + (size_t)(ct * 16 + m) * DIM + quad * 8;
#pragma unroll
        for (int ks = 0; ks < 4; ++ks) {
            bf16x8 b = *(const bf16x8*)(wr + ks * 32);
            acc[ct] = __builtin_amdgcn_mfma_f32_16x16x32_bf16(a[ks], b, acc[ct], 0, 0, 0);
        }
    }

    // epilogue: bias + bf16 store + masked column stats
#pragma unroll
    for (int ct = 0; ct < 8; ++ct) {
        int col = ct * 16 + m;
        float bv = bias[col];
        float s = 0.f, q = 0.f;
#pragma unroll
        for (int r = 0; r < 4; ++r) {
            int row = rowbase + quad * 4 + r;
            float val = acc[ct][r] + bv;
            if (row < NN) {
                Y[(size_t)row * DIM + col] = (unsigned short)f2bf(val);
                s += val;
                q = fmaf(val, val, q);
            }
        }
        s += __shfl_xor(s, 16); s += __shfl_xor(s, 32);
        q += __shfl_xor(q, 16); q += __shfl_xor(q, 32);
        if (quad == 0) { red[w * 256 + col] = s; red[w * 256 + 128 + col] = q; }
    }
    __syncthreads();
    if (t < 256) {
        float tot = red[t] + red[256 + t] + red[512 + t] + red[768 + t];
        unsafeAtomicAdd(&ostat[t], tot);
    }
}

// Per-graph sum pooling (sorted graph_ids), bf16 input, fp32 accumulation.
// 32 nodes/block (3125 blocks). BN fold in-register (TR=1).
template<int TR>
__global__ void pool_nodes(const unsigned* __restrict__ hq, const int* __restrict__ gid,
                           const float* __restrict__ stat, const float* __restrict__ gamma,
                           const float* __restrict__ beta, float* __restrict__ pg) {
    const int lane = threadIdx.x;            // 64 threads, feature pair per lane
    int start = blockIdx.x * 32;
    int end = start + 32;
    if (end > NN) end = NN;
    int f = lane * 2;
    float a0 = 0.f, c0 = 0.f, a1 = 0.f, c1 = 0.f;
    if (TR) {
        bn_coef(stat, gamma, beta, f, a0, c0);
        bn_coef(stat, gamma, beta, f + 1, a1, c1);
    }
    int cur = gid[start];
    float acc0 = 0.f, acc1 = 0.f;
    for (int i = start; i < end; ++i) {
        int g = gid[i];
        if (g != cur) {
            unsafeAtomicAdd(&pg[cur * DIM + f], acc0);
            unsafeAtomicAdd(&pg[cur * DIM + f + 1], acc1);
            acc0 = 0.f; acc1 = 0.f;
            cur = g;
        }
        unsigned u = hq[(size_t)i * 64 + lane];
        float x0 = bf_lo(u), x1 = bf_hi(u);
        if (TR) {
            x0 = fmaxf(fmaf(x0, a0, c0), 0.f);
            x1 = fmaxf(fmaf(x1, a1, c1), 0.f);
        }
        acc0 += x0; acc1 += x1;
    }
    unsafeAtomicAdd(&pg[cur * DIM + f], acc0);
    unsafeAtomicAdd(&pg[cur * DIM + f + 1], acc1);
}

__global__ void final_score(const float* __restrict__ pg, const float* __restrict__ predW,
                            const float* __restrict__ predb, float* __restrict__ out) {
    int g = blockIdx.x;
    int o = threadIdx.x;
    float acc = 0.f;
    for (int l = 0; l <= NL; ++l) {
        acc += predb[l * OUTD + o];
        const float* pgr = pg + ((size_t)l * NG + g) * DIM;
        const float* w = predW + (size_t)l * DIM * OUTD;
#pragma unroll 8
        for (int k = 0; k < DIM; ++k)
            acc = fmaf(pgr[k], w[k * OUTD + o], acc);
    }
    out[g * OUTD + o] = acc;
}

extern "C" void kernel_launch(void* const* d_in, const int* in_sizes, int n_in,
                              void* d_out, int out_size, void* d_ws, size_t ws_size,
                              hipStream_t stream) {
    const float* x     = (const float*)d_in[0];
    const int*   esrc  = (const int*)d_in[1];
    const int*   edst  = (const int*)d_in[2];
    const int*   gid   = (const int*)d_in[3];
    const float* eps   = (const float*)d_in[4];
    const float* W1    = (const float*)d_in[5];
    const float* b1    = (const float*)d_in[6];
    const float* g1    = (const float*)d_in[7];
    const float* be1   = (const float*)d_in[8];
    const float* W2    = (const float*)d_in[9];
    const float* b2    = (const float*)d_in[10];
    const float* g2    = (const float*)d_in[11];
    const float* be2   = (const float*)d_in[12];
    const float* predW = (const float*)d_in[13];
    const float* predb = (const float*)d_in[14];
    float* out = (float*)d_out;

    // ws layout (~85 MB): 3 bf16 node buffers + Wt + [PG|STATS|DEG one-memset
    // region] + CSR arrays
    unsigned short* XB = (unsigned short*)d_ws;
    unsigned short* A  = XB + (size_t)NN * DIM;
    unsigned short* B  = A + (size_t)NN * DIM;
    unsigned short* WT = B + (size_t)NN * DIM;
    float* PG    = (float*)(WT + 8 * DIM * DIM);
    float* STATS = PG + 5 * NG * DIM;          // 4 layers x 512: [S1|SQ1|S2|SQ2]
    int* DEG  = (int*)(STATS + NL * 512);
    int* LOC  = DEG + NN;
    int* OFFS = LOC + NN;
    int* CUR  = OFFS + NN;
    int* BS   = CUR + NN;
    int* PERM = BS + 128;

    // one memset covers PG + all per-layer stats + DEG (contiguous)
    hipMemsetAsync(PG, 0, (5 * NG * DIM + NL * 512) * sizeof(float) + NN * sizeof(int),
                   stream);

    // ---- one-time per call: CSR build, x->bf16, transposed bf16 weights
    const int eBlocks = (NE + 255) / 256;
    hist<<<eBlocks, 256, 0, stream>>>(edst, DEG);
    scan_local<<<NB, 256, 0, stream>>>(DEG, LOC, BS);
    scan_sums<<<1, 128, 0, stream>>>(BS);
    scan_add<<<(NN + 255) / 256, 256, 0, stream>>>(LOC, BS, OFFS, CUR);
    scatter_sliced<<<dim3(NSL, (NE + SL_CH - 1) / SL_CH), 256, 0, stream>>>(esrc, edst,
                                                                            CUR, PERM);
    to_bf16<<<(NN * DIM) / 1024, 256, 0, stream>>>(x, (unsigned*)XB);
    build_wt<<<dim3(8, 8), 256, 0, stream>>>(W1, W2, WT);

    const int poolBlocks = (NN + 31) / 32;
    const int aggBlocks  = (NN + 3) / 4;
    const int gemmBlocks = (NN + 63) / 64;

    const unsigned* h = (const unsigned*)XB;
    for (int l = 0; l < NL; ++l) {
        float* STATL = STATS + l * 512;
        if (l == 0) {
            pool_nodes<0><<<poolBlocks, 64, 0, stream>>>(h, gid, nullptr, nullptr, nullptr, PG);
            csr_agg<0><<<aggBlocks, 256, 0, stream>>>(h, OFFS, PERM, eps, l,
                                                      nullptr, nullptr, nullptr, (unsigned*)B);
        } else {
            const float* prevS = STATS + (l - 1) * 512 + 256;
            const float* gg = g2 + (l - 1) * DIM;
            const float* bb = be2 + (l - 1) * DIM;
            pool_nodes<1><<<poolBlocks, 64, 0, stream>>>(h, gid, prevS, gg, bb,
                                                         PG + l * NG * DIM);
            csr_agg<1><<<aggBlocks, 256, 0, stream>>>(h, OFFS, PERM, eps, l,
                                                      prevS, gg, bb, (unsigned*)B);
        }
        gemm_mfma<0><<<gemmBlocks, 256, 0, stream>>>(B, WT + (size_t)(2 * l) * DIM * DIM,
                                                     b1 + l * DIM, nullptr, nullptr, nullptr,
                                                     B, STATL);
        gemm_mfma<1><<<gemmBlocks, 256, 0, stream>>>(B, WT + (size_t)(2 * l + 1) * DIM * DIM,
                                                     b2 + l * DIM, STATL, g1 + l * DIM,
                                                     be1 + l * DIM, A, STATL + 256);
        h = (const unsigned*)A;
    }
    pool_nodes<1><<<poolBlocks, 64, 0, stream>>>(h, gid, STATS + (NL - 1) * 512 + 256,
                                                 g2 + (NL - 1) * DIM, be2 + (NL - 1) * DIM,
                                                 PG + NL * NG * DIM);
    final_score<<<NG, OUTD, 0, stream>>>(PG, predW, predb, out);
}

// Round 9
// 943.557 us; speedup vs baseline: 1.4128x; 1.2704x over previous
//
#include <hip/hip_runtime.h>

#define NN 100000
#define NE 1600000
#define NG 128
#define DIM 128
#define OUTD 64
#define NL 4
#define SCAN_B 1024
#define NB ((NN + SCAN_B - 1) / SCAN_B)   // 98 scan blocks
#define NSL 8                              // XCD slices for scatter/hist
#define SLN 12500                          // nodes per slice
#define SL_CH 4096                         // edges per chunk

typedef __attribute__((ext_vector_type(8))) short bf16x8;
typedef __attribute__((ext_vector_type(4))) float floatx4;

__device__ __forceinline__ float bf_lo(unsigned u) {
    union { unsigned u; float f; } c; c.u = u << 16; return c.f;
}
__device__ __forceinline__ float bf_hi(unsigned u) {
    union { unsigned u; float f; } c; c.u = u & 0xffff0000u; return c.f;
}
__device__ __forceinline__ unsigned f2bf(float x) {   // RNE
    union { float f; unsigned u; } c; c.f = x;
    return (c.u + 0x7fffu + ((c.u >> 16) & 1u)) >> 16;
}
__device__ __forceinline__ float bfs2f(short s) {
    union { unsigned u; float f; } c; c.u = ((unsigned)(unsigned short)s) << 16; return c.f;
}

// BN(train) fold: from stat = [sum(128) | sumsq(128)] derive a,c: bn(x)=a*x+c
__device__ __forceinline__ void bn_coef(const float* __restrict__ stat,
                                        const float* __restrict__ gamma,
                                        const float* __restrict__ beta,
                                        int f, float& a, float& c) {
    float mu = stat[f] * (1.0f / NN);
    float var = fmaf(-mu, mu, stat[DIM + f] * (1.0f / NN));
    a = gamma[f] * rsqrtf(var + 1e-5f);
    c = fmaf(-mu, a, beta[f]);
}

// ---------------------------------------------------------------------------
// CSR build, node-granular cursors. hist is XCD-sliced like the scatter:
// slice s only touches deg[s*12500 .. +12500) (50KB window, one XCD's L2).
__global__ void hist_sliced(const int* __restrict__ edst, int* __restrict__ deg) {
    const unsigned lo = blockIdx.x * SLN, hi = lo + SLN;
    int base = blockIdx.y * SL_CH;
    int end = base + SL_CH; if (end > NE) end = NE;
    for (int e = base + threadIdx.x; e < end; e += 256) {
        unsigned d = (unsigned)edst[e];
        if (d >= lo && d < hi) atomicAdd(&deg[d], 1);
    }
}

__global__ void scan_local(const int* __restrict__ deg, int* __restrict__ loc,
                           int* __restrict__ bsums) {
    __shared__ int s[256];
    int base = blockIdx.x * SCAN_B + threadIdx.x * 4;
    int d0 = 0, d1 = 0, d2 = 0, d3 = 0;
    if (base + 0 < NN) d0 = deg[base + 0];
    if (base + 1 < NN) d1 = deg[base + 1];
    if (base + 2 < NN) d2 = deg[base + 2];
    if (base + 3 < NN) d3 = deg[base + 3];
    int t4 = d0 + d1 + d2 + d3;
    s[threadIdx.x] = t4;
    __syncthreads();
    for (int off = 1; off < 256; off <<= 1) {
        int v = (threadIdx.x >= off) ? s[threadIdx.x - off] : 0;
        __syncthreads();
        s[threadIdx.x] += v;
        __syncthreads();
    }
    int excl = s[threadIdx.x] - t4;
    if (base + 0 < NN) loc[base + 0] = excl;
    if (base + 1 < NN) loc[base + 1] = excl + d0;
    if (base + 2 < NN) loc[base + 2] = excl + d0 + d1;
    if (base + 3 < NN) loc[base + 3] = excl + d0 + d1 + d2;
    if (threadIdx.x == 255) bsums[blockIdx.x] = s[255];
}

__global__ void scan_sums(int* __restrict__ bsums) {
    __shared__ int s[128];
    int v = (threadIdx.x < NB) ? bsums[threadIdx.x] : 0;
    s[threadIdx.x] = v;
    __syncthreads();
    for (int off = 1; off < 128; off <<= 1) {
        int u = (threadIdx.x >= off) ? s[threadIdx.x - off] : 0;
        __syncthreads();
        s[threadIdx.x] += u;
        __syncthreads();
    }
    if (threadIdx.x < NB) bsums[threadIdx.x] = s[threadIdx.x] - v;  // exclusive
}

__global__ void scan_add(const int* __restrict__ loc, const int* __restrict__ bsums,
                         int* __restrict__ offs, int* __restrict__ cur) {
    int i = blockIdx.x * 256 + threadIdx.x;
    if (i < NN) {
        int o = loc[i] + bsums[i >> 10];
        offs[i] = o;
        cur[i] = o;
    }
}

// XCD-sliced scatter: slice s (blockIdx.x) only handles dst in its 12500-node
// range; its ~800KB perm window stays one-XCD L2-resident until lines fill.
__global__ void scatter_sliced(const int* __restrict__ esrc, const int* __restrict__ edst,
                               int* __restrict__ cur, int* __restrict__ perm) {
    const unsigned lo = blockIdx.x * SLN, hi = lo + SLN;
    int base = blockIdx.y * SL_CH;
    int end = base + SL_CH; if (end > NE) end = NE;
    for (int e = base + threadIdx.x; e < end; e += 256) {
        unsigned d = (unsigned)edst[e];
        if (d >= lo && d < hi) {
            int pos = atomicAdd(&cur[d], 1);
            perm[pos] = esrc[e];
        }
    }
}

// ---------------------------------------------------------------------------
// fp32 -> bf16 convert (x once per call)
__global__ void to_bf16(const float* __restrict__ x, unsigned* __restrict__ xb) {
    size_t i = ((size_t)blockIdx.x * 256 + threadIdx.x) * 4;
    float4 v = *(const float4*)(x + i);
    uint2 o;
    o.x = f2bf(v.x) | (f2bf(v.y) << 16);
    o.y = f2bf(v.z) | (f2bf(v.w) << 16);
    *(uint2*)(xb + i / 2) = o;
}

// Build Wt[mat][n][k] bf16 from 8 fp32 weight matrices (once per call).
__global__ void build_wt(const float* __restrict__ W1, const float* __restrict__ W2,
                         unsigned short* __restrict__ Wt) {
    int b = blockIdx.x;              // 0..7: layer = b>>1, which = b&1
    const float* W = ((b & 1) ? W2 : W1) + (size_t)(b >> 1) * DIM * DIM;
    unsigned short* O = Wt + (size_t)b * DIM * DIM;
    int i = blockIdx.y * 2048 + threadIdx.x;
    for (int j = 0; j < 8; ++j, i += 256) {
        int k = i >> 7, n = i & 127;
        O[n * DIM + k] = (unsigned short)f2bf(W[i]);
    }
}

// ---------------------------------------------------------------------------
// Pull aggregation in bf16: out[n] = (1+eps)*T(h[n]) + sum_{src} T(h[src]).
// 256 threads = 4 waves; wave = 1 node; lane owns feature pair (dword).
// Thin-wave shape + one-iteration index prefetch (R8-proven, 76.8us).
template<int TR>
__global__ void csr_agg(const unsigned* __restrict__ hq, const int* __restrict__ offs,
                        const int* __restrict__ perm, const float* __restrict__ eps, int l,
                        const float* __restrict__ stat, const float* __restrict__ gamma,
                        const float* __restrict__ beta, unsigned* __restrict__ outq) {
    int node = blockIdx.x * 4 + (threadIdx.x >> 6);
    int lane = threadIdx.x & 63;
    if (node >= NN) return;
    int start = offs[node];
    int end = (node == NN - 1) ? NE : offs[node + 1];
    int f = lane * 2;
    float a0 = 0.f, c0 = 0.f, a1 = 0.f, c1 = 0.f;
    if (TR) {
        bn_coef(stat, gamma, beta, f, a0, c0);
        bn_coef(stat, gamma, beta, f + 1, a1, c1);
    }
    unsigned v = hq[(size_t)node * 64 + lane];
    float x0 = bf_lo(v), x1 = bf_hi(v);
    if (TR) {
        x0 = fmaxf(fmaf(x0, a0, c0), 0.f);
        x1 = fmaxf(fmaf(x1, a1, c1), 0.f);
    }
    float e1 = 1.0f + eps[l];
    float acc0 = e1 * x0, acc1 = e1 * x1;

    int j = start;
    int nidx[8];
    bool have = (j + 7 < end);
    if (have) {
#pragma unroll
        for (int q = 0; q < 8; ++q) nidx[q] = perm[j + q];
    }
    while (have) {
        unsigned u[8];
#pragma unroll
        for (int q = 0; q < 8; ++q)
            u[q] = hq[(size_t)nidx[q] * 64 + lane];
        j += 8;
        have = (j + 7 < end);
        if (have) {
#pragma unroll
            for (int q = 0; q < 8; ++q) nidx[q] = perm[j + q];   // overlaps gathers
        }
        float s0 = 0.f, s1 = 0.f;
#pragma unroll
        for (int q = 0; q < 8; ++q) {
            float p0 = bf_lo(u[q]), p1 = bf_hi(u[q]);
            if (TR) {
                p0 = fmaxf(fmaf(p0, a0, c0), 0.f);
                p1 = fmaxf(fmaf(p1, a1, c1), 0.f);
            }
            s0 += p0; s1 += p1;
        }
        acc0 += s0; acc1 += s1;
    }
    for (; j < end; ++j) {
        unsigned u0 = hq[(size_t)perm[j] * 64 + lane];
        float p0 = bf_lo(u0), p1 = bf_hi(u0);
        if (TR) {
            p0 = fmaxf(fmaf(p0, a0, c0), 0.f);
            p1 = fmaxf(fmaf(p1, a1, c1), 0.f);
        }
        acc0 += p0; acc1 += p1;
    }
    outq[(size_t)node * 64 + lane] = f2bf(acc0) | (f2bf(acc1) << 16);
}

// ---------------------------------------------------------------------------
// Y[NN x 128] = T(X) @ W + bias via mfma_f32_16x16x32_bf16.
// 128 rows/block (R6 shape) + Wt staged once per block into LDS with a
// 16B-chunk XOR swizzle (chunk ^ (row&15)) -> ds_read_b128 at the 8-cyc
// floor, no per-wave L2 round-trips for B. A-loads issued before the staging
// barrier to overlap. red[] aliases Ws after the k-loop.
template<int TR>
__global__ __launch_bounds__(256, 2)
void gemm_mfma(const unsigned short* __restrict__ X, const unsigned short* __restrict__ Wt,
               const float* __restrict__ bias,
               const float* __restrict__ stat, const float* __restrict__ gamma,
               const float* __restrict__ beta,
               unsigned short* __restrict__ Y, float* __restrict__ ostat) {
    __shared__ unsigned short Ws[DIM * DIM];      // 32KB swizzled weight tile
    __shared__ float tatc[2 * DIM];
    float* red = (float*)Ws;                      // reused after k-loop
    const int t = threadIdx.x;
    const int w = t >> 6, lane = t & 63;
    const int quad = lane >> 4, m = lane & 15;
    const int rowbase = blockIdx.x * 128 + w * 32;

    // stage Wt -> LDS (coalesced 16B chunks; chunk c of row r at c ^ (r&15))
#pragma unroll
    for (int i = 0; i < 8; ++i) {
        int chunk = t + i * 256;                  // 2048 chunks of 16B
        int r = chunk >> 4, c = chunk & 15;
        ((uint4*)Ws)[(r << 4) | (c ^ (r & 15))] = ((const uint4*)Wt)[chunk];
    }
    if (TR && t < DIM) {
        float a, c;
        bn_coef(stat, gamma, beta, t, a, c);
        tatc[t] = a; tatc[DIM + t] = c;
    }

    // A-tile raw loads (overlap LDS staging; transform applied after barrier)
    bf16x8 a[2][4];
#pragma unroll
    for (int rt = 0; rt < 2; ++rt) {
        int row = rowbase + rt * 16 + m;
        if (row > NN - 1) row = NN - 1;
        const unsigned short* xr = X + (size_t)row * DIM + quad * 8;
#pragma unroll
        for (int ks = 0; ks < 4; ++ks)
            a[rt][ks] = *(const bf16x8*)(xr + ks * 32);
    }
    __syncthreads();
    if (TR) {
#pragma unroll
        for (int rt = 0; rt < 2; ++rt)
#pragma unroll
            for (int ks = 0; ks < 4; ++ks) {
                int kk = ks * 32 + quad * 8;
                bf16x8 v = a[rt][ks];
#pragma unroll
                for (int j = 0; j < 8; ++j) {
                    float fv = bfs2f(v[j]);
                    fv = fmaxf(fmaf(fv, tatc[kk + j], tatc[DIM + kk + j]), 0.f);
                    v[j] = (short)f2bf(fv);
                }
                a[rt][ks] = v;
            }
    }

    floatx4 acc[2][8];
#pragma unroll
    for (int rt = 0; rt < 2; ++rt)
#pragma unroll
        for (int ct = 0; ct < 8; ++ct) acc[rt][ct] = (floatx4)0.f;

#pragma unroll
    for (int ct = 0; ct < 8; ++ct) {
        const int row = ct * 16 + m;
        const bf16x8* wrow = (const bf16x8*)&Ws[row * DIM];
#pragma unroll
        for (int ks = 0; ks < 4; ++ks) {
            bf16x8 b = wrow[(ks * 4 + quad) ^ m];       // un-swizzle
            acc[0][ct] = __builtin_amdgcn_mfma_f32_16x16x32_bf16(a[0][ks], b, acc[0][ct], 0, 0, 0);
            acc[1][ct] = __builtin_amdgcn_mfma_f32_16x16x32_bf16(a[1][ks], b, acc[1][ct], 0, 0, 0);
        }
    }

    // epilogue: bias + bf16 store + masked column stats
    float sv[8], qv[8];
#pragma unroll
    for (int ct = 0; ct < 8; ++ct) {
        int col = ct * 16 + m;
        float bv = bias[col];
        float s = 0.f, q = 0.f;
#pragma unroll
        for (int rt = 0; rt < 2; ++rt) {
#pragma unroll
            for (int r = 0; r < 4; ++r) {
                int row = rowbase + rt * 16 + quad * 4 + r;
                float val = acc[rt][ct][r] + bv;
                if (row < NN) {
                    Y[(size_t)row * DIM + col] = (unsigned short)f2bf(val);
                    s += val;
                    q = fmaf(val, val, q);
                }
            }
        }
        s += __shfl_xor(s, 16); s += __shfl_xor(s, 32);
        q += __shfl_xor(q, 16); q += __shfl_xor(q, 32);
        sv[ct] = s; qv[ct] = q;
    }
    __syncthreads();                               // done reading Ws -> reuse as red
#pragma unroll
    for (int ct = 0; ct < 8; ++ct) {
        int col = ct * 16 + m;
        if (quad == 0) { red[w * 256 + col] = sv[ct]; red[w * 256 + 128 + col] = qv[ct]; }
    }
    __syncthreads();
    if (t < 256) {
        float tot = red[t] + red[256 + t] + red[512 + t] + red[768 + t];
        unsafeAtomicAdd(&ostat[t], tot);
    }
}

// Per-graph sum pooling (sorted graph_ids), bf16 input, fp32 accumulation.
// 32 nodes/block (3125 blocks). BN fold in-register (TR=1).
template<int TR>
__global__ void pool_nodes(const unsigned* __restrict__ hq, const int* __restrict__ gid,
                           const float* __restrict__ stat, const float* __restrict__ gamma,
                           const float* __restrict__ beta, float* __restrict__ pg) {
    const int lane = threadIdx.x;            // 64 threads, feature pair per lane
    int start = blockIdx.x * 32;
    int end = start + 32;
    if (end > NN) end = NN;
    int f = lane * 2;
    float a0 = 0.f, c0 = 0.f, a1 = 0.f, c1 = 0.f;
    if (TR) {
        bn_coef(stat, gamma, beta, f, a0, c0);
        bn_coef(stat, gamma, beta, f + 1, a1, c1);
    }
    int cur = gid[start];
    float acc0 = 0.f, acc1 = 0.f;
    for (int i = start; i < end; ++i) {
        int g = gid[i];
        if (g != cur) {
            unsafeAtomicAdd(&pg[cur * DIM + f], acc0);
            unsafeAtomicAdd(&pg[cur * DIM + f + 1], acc1);
            acc0 = 0.f; acc1 = 0.f;
            cur = g;
        }
        unsigned u = hq[(size_t)i * 64 + lane];
        float x0 = bf_lo(u), x1 = bf_hi(u);
        if (TR) {
            x0 = fmaxf(fmaf(x0, a0, c0), 0.f);
            x1 = fmaxf(fmaf(x1, a1, c1), 0.f);
        }
        acc0 += x0; acc1 += x1;
    }
    unsafeAtomicAdd(&pg[cur * DIM + f], acc0);
    unsafeAtomicAdd(&pg[cur * DIM + f + 1], acc1);
}

__global__ void final_score(const float* __restrict__ pg, const float* __restrict__ predW,
                            const float* __restrict__ predb, float* __restrict__ out) {
    int g = blockIdx.x;
    int o = threadIdx.x;
    float acc = 0.f;
    for (int l = 0; l <= NL; ++l) {
        acc += predb[l * OUTD + o];
        const float* pgr = pg + ((size_t)l * NG + g) * DIM;
        const float* w = predW + (size_t)l * DIM * OUTD;
#pragma unroll 8
        for (int k = 0; k < DIM; ++k)
            acc = fmaf(pgr[k], w[k * OUTD + o], acc);
    }
    out[g * OUTD + o] = acc;
}

extern "C" void kernel_launch(void* const* d_in, const int* in_sizes, int n_in,
                              void* d_out, int out_size, void* d_ws, size_t ws_size,
                              hipStream_t stream) {
    const float* x     = (const float*)d_in[0];
    const int*   esrc  = (const int*)d_in[1];
    const int*   edst  = (const int*)d_in[2];
    const int*   gid   = (const int*)d_in[3];
    const float* eps   = (const float*)d_in[4];
    const float* W1    = (const float*)d_in[5];
    const float* b1    = (const float*)d_in[6];
    const float* g1    = (const float*)d_in[7];
    const float* be1   = (const float*)d_in[8];
    const float* W2    = (const float*)d_in[9];
    const float* b2    = (const float*)d_in[10];
    const float* g2    = (const float*)d_in[11];
    const float* be2   = (const float*)d_in[12];
    const float* predW = (const float*)d_in[13];
    const float* predb = (const float*)d_in[14];
    float* out = (float*)d_out;

    // ws layout (~85 MB): 3 bf16 node buffers + Wt + [PG|STATS|DEG one-memset
    // region] + CSR arrays
    unsigned short* XB = (unsigned short*)d_ws;
    unsigned short* A  = XB + (size_t)NN * DIM;
    unsigned short* B  = A + (size_t)NN * DIM;
    unsigned short* WT = B + (size_t)NN * DIM;
    float* PG    = (float*)(WT + 8 * DIM * DIM);
    float* STATS = PG + 5 * NG * DIM;          // 4 layers x 512: [S1|SQ1|S2|SQ2]
    int* DEG  = (int*)(STATS + NL * 512);
    int* LOC  = DEG + NN;
    int* OFFS = LOC + NN;
    int* CUR  = OFFS + NN;
    int* BS   = CUR + NN;
    int* PERM = BS + 128;

    // one memset covers PG + all per-layer stats + DEG (contiguous)
    hipMemsetAsync(PG, 0, (5 * NG * DIM + NL * 512) * sizeof(float) + NN * sizeof(int),
                   stream);

    // ---- one-time per call: CSR build, x->bf16, transposed bf16 weights
    const dim3 sliceGrid(NSL, (NE + SL_CH - 1) / SL_CH);
    hist_sliced<<<sliceGrid, 256, 0, stream>>>(edst, DEG);
    scan_local<<<NB, 256, 0, stream>>>(DEG, LOC, BS);
    scan_sums<<<1, 128, 0, stream>>>(BS);
    scan_add<<<(NN + 255) / 256, 256, 0, stream>>>(LOC, BS, OFFS, CUR);
    scatter_sliced<<<sliceGrid, 256, 0, stream>>>(esrc, edst, CUR, PERM);
    to_bf16<<<(NN * DIM) / 1024, 256, 0, stream>>>(x, (unsigned*)XB);
    build_wt<<<dim3(8, 8), 256, 0, stream>>>(W1, W2, WT);

    const int poolBlocks = (NN + 31) / 32;
    const int aggBlocks  = (NN + 3) / 4;
    const int gemmBlocks = (NN + 127) / 128;

    const unsigned* h = (const unsigned*)XB;
    for (int l = 0; l < NL; ++l) {
        float* STATL = STATS + l * 512;
        if (l == 0) {
            pool_nodes<0><<<poolBlocks, 64, 0, stream>>>(h, gid, nullptr, nullptr, nullptr, PG);
            csr_agg<0><<<aggBlocks, 256, 0, stream>>>(h, OFFS, PERM, eps, l,
                                                      nullptr, nullptr, nullptr, (unsigned*)B);
        } else {
            const float* prevS = STATS + (l - 1) * 512 + 256;
            const float* gg = g2 + (l - 1) * DIM;
            const float* bb = be2 + (l - 1) * DIM;
            pool_nodes<1><<<poolBlocks, 64, 0, stream>>>(h, gid, prevS, gg, bb,
                                                         PG + l * NG * DIM);
            csr_agg<1><<<aggBlocks, 256, 0, stream>>>(h, OFFS, PERM, eps, l,
                                                      prevS, gg, bb, (unsigned*)B);
        }
        gemm_mfma<0><<<gemmBlocks, 256, 0, stream>>>(B, WT + (size_t)(2 * l) * DIM * DIM,
                                                     b1 + l * DIM, nullptr, nullptr, nullptr,
                                                     B, STATL);
        gemm_mfma<1><<<gemmBlocks, 256, 0, stream>>>(B, WT + (size_t)(2 * l + 1) * DIM * DIM,
                                                     b2 + l * DIM, STATL, g1 + l * DIM,
                                                     be1 + l * DIM, A, STATL + 256);
        h = (const unsigned*)A;
    }
    pool_nodes<1><<<poolBlocks, 64, 0, stream>>>(h, gid, STATS + (NL - 1) * 512 + 256,
                                                 g2 + (NL - 1) * DIM, be2 + (NL - 1) * DIM,
                                                 PG + NL * NG * DIM);
    final_score<<<NG, OUTD, 0, stream>>>(PG, predW, predb, out);
}